// Round 7
// baseline (159.559 us; speedup 1.0000x reference)
//
#include <hip/hip_runtime.h>
#include <cstdint>

#define N_ROWS 32768
#define KDIM 1024
#define DDIM 256
#define TS 8192  // u16 per 16-KB code tile (32 codes x 256 dims)

typedef __attribute__((ext_vector_type(8))) short bf16x8;
typedef __attribute__((ext_vector_type(4))) float f32x4;

__device__ __forceinline__ unsigned short f2bf(float f) {
  unsigned int u = __float_as_uint(f);
  u += 0x7FFFu + ((u >> 16) & 1u);
  return (unsigned short)(u >> 16);
}

// async global->LDS, 16B per lane. LDS dest = wave-uniform base + lane*16.
__device__ __forceinline__ void gload_lds16(const void* g, void* l) {
  __builtin_amdgcn_global_load_lds(
      (const __attribute__((address_space(1))) unsigned int*)(uintptr_t)g,
      (__attribute__((address_space(3))) unsigned int*)(unsigned int)(uintptr_t)l,
      16, 0, 0);
}

// stage one 16-KB tile with a 256-thread block (4 insts/lane)
#define STAGE16(srcp, dstp)                                   \
  {                                                           \
    const char* _s = (const char*)(srcp);                     \
    char* _d = (char*)(dstp);                                 \
    _Pragma("unroll") for (int _i = 0; _i < 4; ++_i) {        \
      const int _off = _i * 4096 + wid * 1024 + lane * 16;    \
      gload_lds16(_s + _off, _d + _off);                      \
    }                                                         \
  }

// Global layouts (u16 offsets), XOR chunk swizzle baked in (chunk = 8 u16):
// Cn32 [t=c>>5][kb=d>>5][c&31][32]: t*TS + kb*1024 + (c&31)*32 + ((((d&31)>>3)^(c&3))*8) + (d&7)
// CnT32[t=c>>5][d][32]:             t*TS + d*32 + (((c&31)>>3 ^ (d&3))*8) + ((c&31)&7)

// ---------------- normalize codebook -> Cn32, CnT32 (bf16, swizzled)
__global__ __launch_bounds__(256) void k_norm_cb(const float* __restrict__ cb,
                                                 unsigned short* __restrict__ Cn,
                                                 unsigned short* __restrict__ CnT) {
  const int wid = threadIdx.x >> 6, lane = threadIdx.x & 63;
  const int k = blockIdx.x * 4 + wid;  // 1024 codes
  float4 v = ((const float4*)(cb + (size_t)k * DDIM))[lane];
  float s = v.x * v.x + v.y * v.y + v.z * v.z + v.w * v.w;
#pragma unroll
  for (int m = 32; m; m >>= 1) s += __shfl_xor(s, m, 64);
  const float rn = 1.0f / sqrtf(s);
  ushort4 p;
  p.x = f2bf(v.x * rn); p.y = f2bf(v.y * rn);
  p.z = f2bf(v.z * rn); p.w = f2bf(v.w * rn);
  // Cn32: d = lane*4
  const int t = k >> 5, c31 = k & 31;
  *(ushort4*)(Cn + (size_t)t * TS + (lane >> 3) * 1024 + c31 * 32 +
              ((((lane & 7) >> 1) ^ (k & 3)) * 8) + (lane & 1) * 4) = p;
  // CnT32
  const int ch = c31 >> 3, cw = c31 & 7;
  const unsigned short pv[4] = {p.x, p.y, p.z, p.w};
#pragma unroll
  for (int j = 0; j < 4; ++j) {
    const int d = lane * 4 + j;
    CnT[(size_t)t * TS + d * 32 + ((ch ^ j) * 8) + cw] = pv[j];
  }
}

// ---------------- k_all: one block = 64 rows, 256 thr, 2 blocks/CU.
// areg: 32 rows x 256 k per wave in registers (loaded once).
// Ring: 4 x 16-KB code-tile slots. Pass A: 1 barrier/kt. Pass B: 1 barrier/kt
// (Ps double-buffered). Slot/buffer lifetimes barrier-separated by design.
__global__ __launch_bounds__(256, 2) void k_all(const float* __restrict__ x,
                                                const unsigned short* __restrict__ Cn,
                                                const unsigned short* __restrict__ CnT,
                                                float* __restrict__ part,
                                                float* __restrict__ lse_part,
                                                float* __restrict__ out) {
  __shared__ unsigned short Sl[4][TS];       // 64 KB ring; Sl[2..3] doubles as Xs transient
  __shared__ unsigned short Ps[2][64 * 40];  // 10 KB, stride 40 u16, chunk-swizzled
  __shared__ float csl[1024];
  __shared__ float rs[64], qs[64], irl[64];

  const int tid = threadIdx.x, wid = tid >> 6, lane = tid & 63;
  const int l15 = lane & 15, l4 = lane >> 4;
  const int wm = wid >> 1, wn = wid & 1;  // wave: 32 rows x (16 cols S / 128 d PV)
  const int rb = blockIdx.x;              // 512 blocks x 64 rows
  if (tid < 64) { rs[tid] = 0.f; qs[tid] = 0.f; }
  for (int j = tid; j < 1024; j += 256) csl[j] = 0.f;

  // early: stage Cn(0)->Sl[0], Cn(1)->Sl[1] (overlaps norm phase)
  STAGE16(Cn, Sl[0]);
  STAGE16((const char*)Cn + TS * 2, Sl[1]);

  // norm: rows -> Xs (= Sl[2..3], plain [kb][64][32] layout)
  unsigned short* Xs = &Sl[2][0];
#pragma unroll
  for (int p16 = 0; p16 < 16; ++p16) {
    const int row = p16 * 4 + wid;
    float4 v = ((const float4*)(x + (size_t)(rb * 64 + row) * DDIM))[lane];
    float s = v.x * v.x + v.y * v.y + v.z * v.z + v.w * v.w;
#pragma unroll
    for (int m = 32; m; m >>= 1) s += __shfl_xor(s, m, 64);
    const float rn = 1.0f / sqrtf(s);
    ushort4 p;
    p.x = f2bf(v.x * rn); p.y = f2bf(v.y * rn);
    p.z = f2bf(v.z * rn); p.w = f2bf(v.w * rn);
    *(ushort4*)&Xs[(lane >> 3) * 2048 + row * 32 + (lane & 7) * 4] = p;
  }
  __syncthreads();
  // A-fragments -> registers (then Sl[2..3] is recycled by the ring)
  bf16x8 areg[2][8];
#pragma unroll
  for (int mi = 0; mi < 2; ++mi)
#pragma unroll
    for (int kb = 0; kb < 8; ++kb)
      areg[mi][kb] = *(const bf16x8*)&Xs[kb * 2048 + (wm * 32 + mi * 16 + l15) * 32 + l4 * 8];
  __syncthreads();

  const int bsw = (l4 ^ (l15 & 3)) * 8;  // B-fragment chunk swizzle (S phase & CnT)

  // ---------------- Pass A: r = rowsum(exp), q = rowsum(exp^2) ----------------
  float se[2][4], sq[2][4];
#pragma unroll
  for (int mi = 0; mi < 2; ++mi)
#pragma unroll
    for (int reg = 0; reg < 4; ++reg) { se[mi][reg] = 0.f; sq[mi][reg] = 0.f; }
  for (int kt = 0; kt < 32; ++kt) {
    // distance-2 prefetch (wraps to Cn(0),Cn(1) at the tail for pass B)
    STAGE16((const char*)Cn + (size_t)((kt + 2) & 31) * TS * 2, Sl[(kt + 2) & 3]);
    const unsigned short* B = Sl[kt & 3];
    f32x4 acc[2] = {};
#pragma unroll
    for (int kb = 0; kb < 8; ++kb) {
      const bf16x8 b = *(const bf16x8*)&B[kb * 1024 + (wn * 16 + l15) * 32 + bsw];
      acc[0] = __builtin_amdgcn_mfma_f32_16x16x32_bf16(areg[0][kb], b, acc[0], 0, 0, 0);
      acc[1] = __builtin_amdgcn_mfma_f32_16x16x32_bf16(areg[1][kb], b, acc[1], 0, 0, 0);
    }
#pragma unroll
    for (int mi = 0; mi < 2; ++mi)
#pragma unroll
      for (int reg = 0; reg < 4; ++reg) {
        const float e = __expf(acc[mi][reg]);
        se[mi][reg] += e; sq[mi][reg] += e * e;
      }
    __syncthreads();
  }
#pragma unroll
  for (int mi = 0; mi < 2; ++mi)
#pragma unroll
    for (int reg = 0; reg < 4; ++reg) {
#pragma unroll
      for (int m = 1; m < 16; m <<= 1) {
        se[mi][reg] += __shfl_xor(se[mi][reg], m, 64);
        sq[mi][reg] += __shfl_xor(sq[mi][reg], m, 64);
      }
    }
  if (l15 == 0) {
#pragma unroll
    for (int mi = 0; mi < 2; ++mi)
#pragma unroll
      for (int reg = 0; reg < 4; ++reg) {
        const int row = wm * 32 + mi * 16 + l4 * 4 + reg;
        atomicAdd(&rs[row], se[mi][reg]);
        atomicAdd(&qs[row], sq[mi][reg]);
      }
  }
  __syncthreads();
  if (tid < 64) {
    const float r = rs[tid];
    const float ir = 1.0f / r;
    irl[tid] = ir;
    // series-LSE: sum_k exp(e_k/r) = K + 1 + q/(2 r^2)  (|d|~1e-3, err ~1e-9)
    float lse = logf((float)(KDIM + 1) + 0.5f * qs[tid] * ir * ir);
#pragma unroll
    for (int m = 32; m; m >>= 1) lse += __shfl_xor(lse, m, 64);
    if (tid == 0) lse_part[rb] = lse;
  }
  __syncthreads();
  float ir[2][4];
#pragma unroll
  for (int mi = 0; mi < 2; ++mi)
#pragma unroll
    for (int reg = 0; reg < 4; ++reg)
      ir[mi][reg] = irl[wm * 32 + mi * 16 + l4 * 4 + reg];

  // ---------------- Pass B: recompute S, exp->Ps, colsum, PV ----------------
  f32x4 O[2][8] = {};
  const int ps_w = (((wn * 2 + (l15 >> 3)) ^ l4) * 8) + (l15 & 7);  // epi write
  const int ps_r = ((l4 ^ ((l15 >> 2) & 3)) * 8);                   // PV read
#define S_EPI(kt_, Bslot_, Pbuf_)                                                   \
  {                                                                                 \
    const unsigned short* B_ = Sl[Bslot_];                                          \
    f32x4 S_[2] = {};                                                               \
    _Pragma("unroll") for (int kb = 0; kb < 8; ++kb) {                              \
      const bf16x8 b = *(const bf16x8*)&B_[kb * 1024 + (wn * 16 + l15) * 32 + bsw]; \
      S_[0] = __builtin_amdgcn_mfma_f32_16x16x32_bf16(areg[0][kb], b, S_[0], 0, 0, 0); \
      S_[1] = __builtin_amdgcn_mfma_f32_16x16x32_bf16(areg[1][kb], b, S_[1], 0, 0, 0); \
    }                                                                               \
    float cs = 0.f;                                                                 \
    _Pragma("unroll") for (int mi = 0; mi < 2; ++mi)                                \
      _Pragma("unroll") for (int reg = 0; reg < 4; ++reg) {                         \
        const int row = wm * 32 + mi * 16 + l4 * 4 + reg;                           \
        const float e = __expf(S_[mi][reg]);                                        \
        Ps[Pbuf_][row * 40 + ps_w] = f2bf(e);                                       \
        cs += e * ir[mi][reg];                                                      \
      }                                                                             \
    cs += __shfl_xor(cs, 16, 64);                                                   \
    cs += __shfl_xor(cs, 32, 64);                                                   \
    if (lane < 16) atomicAdd(&csl[(kt_) * 32 + wn * 16 + l15], cs);                 \
  }
#define PV_STEP(Pbuf_, Tslot_)                                                       \
  {                                                                                  \
    bf16x8 a2[2], b2[8];                                                             \
    _Pragma("unroll") for (int mi = 0; mi < 2; ++mi)                                 \
      a2[mi] = *(const bf16x8*)&Ps[Pbuf_][(wm * 32 + mi * 16 + l15) * 40 + ps_r];    \
    _Pragma("unroll") for (int ni = 0; ni < 8; ++ni)                                 \
      b2[ni] = *(const bf16x8*)&Sl[Tslot_][(wn * 128 + ni * 16 + l15) * 32 + bsw];   \
    _Pragma("unroll") for (int mi = 0; mi < 2; ++mi)                                 \
      _Pragma("unroll") for (int ni = 0; ni < 8; ++ni)                               \
        O[mi][ni] = __builtin_amdgcn_mfma_f32_16x16x32_bf16(a2[mi], b2[ni], O[mi][ni], 0, 0, 0); \
  }
  // I_B(0): stage CnT(0); S(0)+epi; barrier.  (Cn(1) already staged by pass-A tail)
  STAGE16(CnT, Sl[2]);
  S_EPI(0, 0, 0);
  __syncthreads();
  for (int kt = 1; kt < 32; ++kt) {
    STAGE16((const char*)CnT + (size_t)kt * TS * 2, Sl[2 + (kt & 1)]);
    if (kt <= 30) STAGE16((const char*)Cn + (size_t)(kt + 1) * TS * 2, Sl[(kt + 1) & 1]);
    PV_STEP((kt - 1) & 1, 2 + ((kt - 1) & 1));
    S_EPI(kt, kt & 1, kt & 1);
    __syncthreads();
  }
  PV_STEP(1, 3);

  // out = O * ir
#pragma unroll
  for (int mi = 0; mi < 2; ++mi)
#pragma unroll
    for (int reg = 0; reg < 4; ++reg) {
      const int row = wm * 32 + mi * 16 + l4 * 4 + reg;
      const float irv = ir[mi][reg];
#pragma unroll
      for (int ni = 0; ni < 8; ++ni) {
        const int d = wn * 128 + ni * 16 + l15;
        out[(size_t)(rb * 64 + row) * DDIM + d] = O[mi][ni][reg] * irv;
      }
    }
  __syncthreads();
  for (int j = tid; j < 1024; j += 256) part[(size_t)rb * 1024 + j] = csl[j];
}

// ---------------- final: reduce 512 colsum partials + lse; last block -> loss
__global__ __launch_bounds__(256) void k_final(const float* __restrict__ part,
                                               const float* __restrict__ lse_part,
                                               float* __restrict__ acc,  // S,Q,L,counter
                                               float* __restrict__ out) {
  __shared__ float sh[4][16], shl[4];
  const int tid = threadIdx.x, w = tid >> 6, lane = tid & 63;
  const int l15 = lane & 15, l4 = lane >> 4;
  const int k = blockIdx.x * 16 + l15;
  const int g = w * 4 + l4;  // 16 groups of 32 blocks
  float s = 0.f;
#pragma unroll 8
  for (int m = 0; m < 32; ++m) s += part[(size_t)(g * 32 + m) * 1024 + k];
  s += __shfl_xor(s, 16, 64);
  s += __shfl_xor(s, 32, 64);
  if (lane < 16) sh[w][l15] = s;
  float l = 0.f;
  if (blockIdx.x == 0) {
    l = lse_part[tid] + lse_part[256 + tid];
#pragma unroll
    for (int m = 1; m < 64; m <<= 1) l += __shfl_xor(l, m, 64);
    if (lane == 0) shl[w] = l;
  }
  __syncthreads();
  if (tid < 16) {
    const float cs = sh[0][tid] + sh[1][tid] + sh[2][tid] + sh[3][tid];
    float s1 = cs, s2 = cs * cs;
#pragma unroll
    for (int m = 1; m < 16; m <<= 1) {
      s1 += __shfl_xor(s1, m, 64);
      s2 += __shfl_xor(s2, m, 64);
    }
    if (tid == 0) {
      atomicAdd(&acc[0], s1);
      atomicAdd(&acc[1], s2);
      if (blockIdx.x == 0) atomicAdd(&acc[2], shl[0] + shl[1] + shl[2] + shl[3]);
    }
  }
  __syncthreads();
  if (tid == 0) {
    __threadfence();
    const unsigned int old = atomicAdd((unsigned int*)&acc[3], 1u);
    if (old == 63u) {  // last block: all adds visible
      __threadfence();
      const double S = acc[0], Q = acc[1], L = acc[2];
      const double entropy = (S * L - Q) / (double)N_ROWS;
      const double l1 = S / ((double)N_ROWS * (double)KDIM);
      out[(size_t)N_ROWS * DDIM] = (float)(1000.0 * l1 + 5e-5 * entropy);
    }
  }
}

extern "C" void kernel_launch(void* const* d_in, const int* in_sizes, int n_in,
                              void* d_out, int out_size, void* d_ws, size_t ws_size,
                              hipStream_t stream) {
  const float* x = (const float*)d_in[0];   // [8,4096,256] fp32
  const float* cb = (const float*)d_in[1];  // [1024,256] fp32
  float* out = (float*)d_out;               // recon [8388608] + loss [1]
  char* ws = (char*)d_ws;

  unsigned short* Cn  = (unsigned short*)(ws + 0);         // 524288 B (Cn32 swizzled)
  unsigned short* CnT = (unsigned short*)(ws + 524288);    // 524288 B (CnT32 swizzled)
  float* part         = (float*)(ws + 1048576);            // 2097152 B (512 x 1024)
  float* lse_part     = (float*)(ws + 3145728);            // 2048 B
  float* acc          = (float*)(ws + 3147776);            // 16 B (S,Q,L,counter)

  hipMemsetAsync(acc, 0, 16, stream);
  k_norm_cb<<<256, 256, 0, stream>>>(cb, Cn, CnT);
  k_all<<<512, 256, 0, stream>>>(x, Cn, CnT, part, lse_part, out);
  k_final<<<64, 256, 0, stream>>>(part, lse_part, acc, out);
}